// Round 7
// baseline (231.445 us; speedup 1.0000x reference)
//
#include <hip/hip_runtime.h>
#include <hip/hip_bf16.h>
#include <cstdint>

typedef __bf16 bf16;
typedef bf16 bf16x4v __attribute__((ext_vector_type(4)));
typedef bf16 bf16x8 __attribute__((ext_vector_type(8)));
typedef float f32x4 __attribute__((ext_vector_type(4)));

#define MFMA16(a, b, c) __builtin_amdgcn_mfma_f32_16x16x32_bf16(a, b, c, 0, 0, 0)

struct rawF { f32x4 a, b; };
__device__ inline rawF ldr(const float* p) {
  rawF r; r.a = *(const f32x4*)p; r.b = *(const f32x4*)(p + 4); return r;
}
__device__ inline bf16x8 ldr(const bf16* p) { return *(const bf16x8*)p; }
__device__ inline bf16x8 cv(const rawF& r) {
  bf16x8 o;
#pragma unroll
  for (int i = 0; i < 4; ++i) { o[i] = (bf16)r.a[i]; o[i + 4] = (bf16)r.b[i]; }
  return o;
}
__device__ inline bf16x8 cv(const bf16x8& r) { return r; }
__device__ inline void stC(bf16* C, size_t i, float v) { C[i] = (bf16)v; }
__device__ inline void stC(float* C, size_t i, float v) { C[i] = v; }

// ---- prep: transpose-convert weights fp32 [K][N] -> bf16 [N][K]; z selects W ----
__global__ __launch_bounds__(256) void prep_wt(const float* __restrict__ W0,
                                               const float* __restrict__ W1,
                                               const float* __restrict__ W2,
                                               bf16* __restrict__ Wt, int n) {
  const float* Ws[3] = {W0, W1, W2};
  const float* W = Ws[blockIdx.z];
  bf16* out = Wt + (size_t)blockIdx.z * n * n;
  __shared__ bf16 t[32][33];
  int bx = blockIdx.x * 32, by = blockIdx.y * 32;
  int tx = threadIdx.x & 31, ty = threadIdx.x >> 5;
#pragma unroll
  for (int i = 0; i < 32; i += 8)
    t[ty + i][tx] = (bf16)W[(size_t)(by + ty + i) * n + bx + tx];
  __syncthreads();
#pragma unroll
  for (int i = 0; i < 32; i += 8)
    out[(size_t)(bx + ty + i) * n + by + tx] = t[tx][ty + i];
}

// ---- transpose V bf16 [b*s][D] -> Vt [bh][hd][2048] ----
__global__ __launch_bounds__(256) void vtrans(const bf16* __restrict__ V, bf16* __restrict__ Vt) {
  constexpr int Sn = 2048, Dn = 1024;
  __shared__ bf16 t[32][33];
  int s0 = blockIdx.x * 32, hd0 = blockIdx.y * 32, bh = blockIdx.z;
  int b = bh >> 4, h = bh & 15;
  int tx = threadIdx.x & 31, ty = threadIdx.x >> 5;
#pragma unroll
  for (int i = 0; i < 32; i += 8)
    t[ty + i][tx] = V[(size_t)(b * Sn + s0 + ty + i) * Dn + h * 64 + hd0 + tx];
  __syncthreads();
#pragma unroll
  for (int i = 0; i < 32; i += 8)
    Vt[(size_t)bh * 64 * Sn + (size_t)(hd0 + ty + i) * Sn + s0 + tx] = t[tx][ty + i];
}

// ---- GEMM C[M,N] = A[M,K] @ Bt^T (Bt = bf16 [N][K]); reg-prefetched k-loop ----
// 128x128 tile, BK=32, 256 threads = 4 waves; blockIdx.y selects among 3 B/C pairs.
template <typename TA, typename TC>
__global__ __launch_bounds__(256) void gemm_bt3(const TA* __restrict__ A,
                                                const bf16* __restrict__ Bt0,
                                                const bf16* __restrict__ Bt1,
                                                const bf16* __restrict__ Bt2,
                                                TC* __restrict__ C0, TC* __restrict__ C1,
                                                TC* __restrict__ C2, int M, int N, int K,
                                                int nblk) {
  constexpr int LDA = 40, LDB = 40;
  __shared__ bf16 As[128 * LDA];
  __shared__ bf16 Bs[128 * LDB];
  int tid = threadIdx.x, wave = tid >> 6, lane = tid & 63;
  int la = lane & 15, quad = lane >> 4;
  int wr = (wave >> 1) * 64, wc = (wave & 1) * 64;
  int by = blockIdx.y;
  int sel = by / nblk;
  int n0 = (by - sel * nblk) * 128;
  const bf16* Bm = sel == 0 ? Bt0 : (sel == 1 ? Bt1 : Bt2);
  TC* C = sel == 0 ? C0 : (sel == 1 ? C1 : C2);
  const TA* Ab = A + (size_t)blockIdx.x * 128 * K;

  int ar[2], ac[2];
#pragma unroll
  for (int p = 0; p < 2; ++p) {
    int li = (tid + p * 256) * 8;
    ar[p] = li >> 5; ac[p] = li & 31;
  }

  f32x4 zero = {0.f, 0.f, 0.f, 0.f};
  f32x4 acc[4][4];
#pragma unroll
  for (int i = 0; i < 4; ++i)
#pragma unroll
    for (int j = 0; j < 4; ++j) acc[i][j] = zero;

  decltype(ldr((const TA*)nullptr)) pa[2];
  bf16x8 pb[2];
#pragma unroll
  for (int p = 0; p < 2; ++p) {
    pa[p] = ldr(&Ab[(size_t)ar[p] * K + ac[p]]);
    pb[p] = ldr(&Bm[(size_t)(n0 + ar[p]) * K + ac[p]]);
  }

  for (int k0 = 0; k0 < K; k0 += 32) {
#pragma unroll
    for (int p = 0; p < 2; ++p) {
      *(bf16x8*)&As[ar[p] * LDA + ac[p]] = cv(pa[p]);
      *(bf16x8*)&Bs[ar[p] * LDB + ac[p]] = pb[p];
    }
    __syncthreads();
    int k1 = k0 + 32;
    if (k1 < K) {
#pragma unroll
      for (int p = 0; p < 2; ++p) {
        pa[p] = ldr(&Ab[(size_t)ar[p] * K + k1 + ac[p]]);
        pb[p] = ldr(&Bm[(size_t)(n0 + ar[p]) * K + k1 + ac[p]]);
      }
    }
    bf16x8 af[4], bfr[4];
#pragma unroll
    for (int i = 0; i < 4; ++i)
      af[i] = *(const bf16x8*)&As[(wr + i * 16 + la) * LDA + quad * 8];
#pragma unroll
    for (int j = 0; j < 4; ++j)
      bfr[j] = *(const bf16x8*)&Bs[(wc + j * 16 + la) * LDB + quad * 8];
#pragma unroll
    for (int i = 0; i < 4; ++i)
#pragma unroll
      for (int j = 0; j < 4; ++j) acc[i][j] = MFMA16(af[i], bfr[j], acc[i][j]);
    __syncthreads();
  }
#pragma unroll
  for (int i = 0; i < 4; ++i) {
#pragma unroll
    for (int j = 0; j < 4; ++j) {
      int col = n0 + wc + j * 16 + la;
#pragma unroll
      for (int r = 0; r < 4; ++r) {
        int row = blockIdx.x * 128 + wr + i * 16 + quad * 4 + r;
        stC(C, (size_t)row * N + col, acc[i][j][r]);
      }
    }
  }
}

// ---- flash attention, causal, HD=64; transposed scores (S^T = K@Q^T) ----
// grid (32, 32): one q-tile per block, qt = 31-bx (heavy first, LPT balance).
// Lane owns ONE q-row's softmax state; in-lane reductions + 2 shfl.
// Register prefetch of next K/V tile; packed b64 P-spill; 2 barriers/tile.
__global__ __launch_bounds__(256) void flash_attn(const bf16* __restrict__ Q,
                                                  const bf16* __restrict__ Kg,
                                                  const bf16* __restrict__ Vtg,
                                                  bf16* __restrict__ O) {
  constexpr int D = 1024, S = 2048;
  const int LDK = 72, LDP = 72;
  const float MASK = -3.0e4f;
  const float SCL2 = 0.18033688011112042f;  // log2(e)/sqrt(64)
  __shared__ bf16 Ks[64 * 72];     // [key][hd]
  __shared__ bf16 Vs[64 * 72];     // [hd][key]
  __shared__ bf16 Ps[4][16 * 72];  // per-wave P [q][key]

  int qt = 31 - blockIdx.x;
  int bh = blockIdx.y;
  int b = bh >> 4, h = bh & 15;
  int tid = threadIdx.x, wave = tid >> 6, lane = tid & 63;
  int la = lane & 15, quad = lane >> 4;
  int q0 = qt * 64;
  const size_t base = (size_t)b * S * D + (size_t)h * 64;
  const bf16* Qg = Q + base;
  const bf16* Kb = Kg + base;
  const bf16* Vb = Vtg + (size_t)bh * 64 * S;  // [hd][s]
  int r0 = tid >> 3, c0 = (tid & 7) * 8;

  f32x4 zero = {0.f, 0.f, 0.f, 0.f};

  // Q B-frags (pre-scaled by SCL2)
  bf16x8 aq[2];
  {
    int qrow = q0 + wave * 16 + la;
#pragma unroll
    for (int kc = 0; kc < 2; ++kc) {
      bf16x8 t = *(const bf16x8*)&Qg[(size_t)qrow * D + kc * 32 + quad * 8];
#pragma unroll
      for (int i = 0; i < 8; ++i) t[i] = (bf16)((float)t[i] * SCL2);
      aq[kc] = t;
    }
  }

  f32x4 o[4];
#pragma unroll
  for (int nt = 0; nt < 4; ++nt) o[nt] = zero;
  float m_l = MASK, l_l = 0.f;

  // prefetch tile 0
  bf16x8 kr0 = *(const bf16x8*)&Kb[(size_t)r0 * D + c0];
  bf16x8 kr1 = *(const bf16x8*)&Kb[(size_t)(r0 + 32) * D + c0];
  bf16x8 vr0 = *(const bf16x8*)&Vb[(size_t)r0 * S + c0];
  bf16x8 vr1 = *(const bf16x8*)&Vb[(size_t)(r0 + 32) * S + c0];

  int ntiles = qt + 1;
  for (int t = 0; t < ntiles; ++t) {
    int kb = t * 64;
    *(bf16x8*)&Ks[r0 * LDK + c0] = kr0;
    *(bf16x8*)&Ks[(r0 + 32) * LDK + c0] = kr1;
    *(bf16x8*)&Vs[r0 * LDK + c0] = vr0;
    *(bf16x8*)&Vs[(r0 + 32) * LDK + c0] = vr1;
    __syncthreads();
    if (t + 1 < ntiles) {
      int kb2 = kb + 64;
      kr0 = *(const bf16x8*)&Kb[(size_t)(kb2 + r0) * D + c0];
      kr1 = *(const bf16x8*)&Kb[(size_t)(kb2 + r0 + 32) * D + c0];
      vr0 = *(const bf16x8*)&Vb[(size_t)r0 * S + kb2 + c0];
      vr1 = *(const bf16x8*)&Vb[(size_t)(r0 + 32) * S + kb2 + c0];
    }

    // S^T = K @ Q^T : lane holds S[q=la][key = kb + nt*16 + quad*4 + r]
    f32x4 s[4];
#pragma unroll
    for (int nt = 0; nt < 4; ++nt) {
      bf16x8 k0f = *(const bf16x8*)&Ks[(nt * 16 + la) * LDK + quad * 8];
      bf16x8 k1f = *(const bf16x8*)&Ks[(nt * 16 + la) * LDK + 32 + quad * 8];
      f32x4 z = zero;
      z = MFMA16(k0f, aq[0], z);
      z = MFMA16(k1f, aq[1], z);
      s[nt] = z;
    }

    if (t == qt) {  // mask only the diagonal tile
      int qa = q0 + wave * 16 + la;
#pragma unroll
      for (int nt = 0; nt < 4; ++nt)
#pragma unroll
        for (int r = 0; r < 4; ++r) {
          int ka = kb + nt * 16 + quad * 4 + r;
          s[nt][r] = (ka > qa) ? MASK : s[nt][r];
        }
    }

    // online softmax: in-lane over 16 keys, then cross-quad butterfly
    float mx = m_l;
#pragma unroll
    for (int nt = 0; nt < 4; ++nt)
#pragma unroll
      for (int r = 0; r < 4; ++r) mx = fmaxf(mx, s[nt][r]);
    mx = fmaxf(mx, __shfl_xor(mx, 16, 64));
    mx = fmaxf(mx, __shfl_xor(mx, 32, 64));
    float alpha = exp2f(m_l - mx);
    float rs = 0.f;
#pragma unroll
    for (int nt = 0; nt < 4; ++nt)
#pragma unroll
      for (int r = 0; r < 4; ++r) {
        float p = exp2f(s[nt][r] - mx);
        s[nt][r] = p;
        rs += p;
      }
    rs += __shfl_xor(rs, 16, 64);
    rs += __shfl_xor(rs, 32, 64);
    l_l = l_l * alpha + rs;
    m_l = mx;

    // spill P packed (wave-private; in-wave LDS ordering is safe)
#pragma unroll
    for (int nt = 0; nt < 4; ++nt) {
      bf16x4v pk;
#pragma unroll
      for (int r = 0; r < 4; ++r) pk[r] = (bf16)s[nt][r];
      *(bf16x4v*)&Ps[wave][la * LDP + nt * 16 + quad * 4] = pk;
    }

    // rescale O rows: alpha lives at lane la==row; broadcast
    float ab[4];
#pragma unroll
    for (int r = 0; r < 4; ++r) ab[r] = __shfl(alpha, quad * 4 + r, 64);
#pragma unroll
    for (int nt = 0; nt < 4; ++nt)
#pragma unroll
      for (int r = 0; r < 4; ++r) o[nt][r] *= ab[r];

    // O += P @ V
#pragma unroll
    for (int kc = 0; kc < 2; ++kc) {
      bf16x8 ap = *(const bf16x8*)&Ps[wave][la * LDP + kc * 32 + quad * 8];
#pragma unroll
      for (int nt = 0; nt < 4; ++nt) {
        bf16x8 bv = *(const bf16x8*)&Vs[(nt * 16 + la) * LDK + kc * 32 + quad * 8];
        o[nt] = MFMA16(ap, bv, o[nt]);
      }
    }
    __syncthreads();  // protect Ks/Vs for next tile
  }

  // epilogue: l at lane la==row; broadcast, normalize, store
  float inv[4];
#pragma unroll
  for (int r = 0; r < 4; ++r) {
    float lv = __shfl(l_l, quad * 4 + r, 64);
    inv[r] = (lv > 1e-30f) ? 1.0f / lv : 0.0f;
  }
#pragma unroll
  for (int nt = 0; nt < 4; ++nt) {
    int hd = nt * 16 + la;
#pragma unroll
    for (int r = 0; r < 4; ++r) {
      int row = q0 + wave * 16 + quad * 4 + r;
      O[base + (size_t)row * D + hd] = (bf16)(o[nt][r] * inv[r]);
    }
  }
}

extern "C" void kernel_launch(void* const* d_in, const int* in_sizes, int n_in,
                              void* d_out, int out_size, void* d_ws, size_t ws_size,
                              hipStream_t stream) {
  constexpr int B = 2, S = 2048, D = 1024;
  constexpr int M = B * S;
  constexpr size_t WN = (size_t)D * D;
  constexpr size_t XN = (size_t)M * D;

  const float* x = (const float*)d_in[0];
  const float* Wq = (const float*)d_in[1];
  const float* Wk = (const float*)d_in[2];
  const float* Wv = (const float*)d_in[3];
  const float* Wo = (const float*)d_in[4];
  float* out = (float*)d_out;

  if (ws_size < 2 * XN * sizeof(bf16)) return;
  // ws [0,8MB): Qb (flash O aliases). ws [8,16MB): time-shared region —
  //   phase 1: Wq^T,Wk^T,Wv^T (6 MB) for QKV gemm; phase 2: Vtg (8 MB) for
  //   flash (weights dead); phase 3: Wo^T (2 MB) for final gemm (Vtg dead).
  bf16* Qb = (bf16*)d_ws;
  bf16* R2 = Qb + XN;       // shared region
  bf16* Kb = (bf16*)d_out;  // d_out[0,8MB): K (dead before final gemm writes)
  bf16* Vb = Kb + XN;       // d_out[8,16MB): V (dead after vtrans)

  // phase 1: weights^T + QKV projections
  prep_wt<<<dim3(32, 32, 3), 256, 0, stream>>>(Wq, Wk, Wv, R2, D);
  gemm_bt3<float, bf16><<<dim3(M / 128, 24), 256, 0, stream>>>(
      x, R2, R2 + WN, R2 + 2 * WN, Qb, Kb, Vb, M, D, D, 8);
  // phase 2: V^T + flash
  vtrans<<<dim3(S / 32, 2, 32), 256, 0, stream>>>(Vb, R2);
  flash_attn<<<dim3(32, 32), 256, 0, stream>>>(Qb, Kb, R2, Qb);
  // phase 3: Wo^T + output projection
  prep_wt<<<dim3(32, 32, 1), 256, 0, stream>>>(Wo, Wo, Wo, R2, D);
  gemm_bt3<bf16, float><<<dim3(M / 128, 8), 256, 0, stream>>>(
      Qb, R2, R2, R2, out, out, out, M, D, D, 8);
}

// Round 8
// 196.622 us; speedup vs baseline: 1.1771x; 1.1771x over previous
//
#include <hip/hip_runtime.h>
#include <hip/hip_bf16.h>
#include <cstdint>

typedef __bf16 bf16;
typedef bf16 bf16x4v __attribute__((ext_vector_type(4)));
typedef bf16 bf16x8 __attribute__((ext_vector_type(8)));
typedef float f32x4 __attribute__((ext_vector_type(4)));

#define MFMA16(a, b, c) __builtin_amdgcn_mfma_f32_16x16x32_bf16(a, b, c, 0, 0, 0)

struct rawF { f32x4 a, b; };
__device__ inline rawF ldr(const float* p) {
  rawF r; r.a = *(const f32x4*)p; r.b = *(const f32x4*)(p + 4); return r;
}
__device__ inline bf16x8 ldr(const bf16* p) { return *(const bf16x8*)p; }
__device__ inline bf16x8 cv(const rawF& r) {
  bf16x8 o;
#pragma unroll
  for (int i = 0; i < 4; ++i) { o[i] = (bf16)r.a[i]; o[i + 4] = (bf16)r.b[i]; }
  return o;
}
__device__ inline bf16x8 cv(const bf16x8& r) { return r; }
__device__ inline void stC(bf16* C, size_t i, float v) { C[i] = (bf16)v; }
__device__ inline void stC(float* C, size_t i, float v) { C[i] = v; }

// ---- prep: transpose-convert weights fp32 [K][N] -> bf16 [N][K]; z selects W ----
__global__ __launch_bounds__(256) void prep_wt(const float* __restrict__ W0,
                                               const float* __restrict__ W1,
                                               const float* __restrict__ W2,
                                               bf16* __restrict__ Wt, int n) {
  const float* Ws[3] = {W0, W1, W2};
  const float* W = Ws[blockIdx.z];
  bf16* out = Wt + (size_t)blockIdx.z * n * n;
  __shared__ bf16 t[32][33];
  int bx = blockIdx.x * 32, by = blockIdx.y * 32;
  int tx = threadIdx.x & 31, ty = threadIdx.x >> 5;
#pragma unroll
  for (int i = 0; i < 32; i += 8)
    t[ty + i][tx] = (bf16)W[(size_t)(by + ty + i) * n + bx + tx];
  __syncthreads();
#pragma unroll
  for (int i = 0; i < 32; i += 8)
    out[(size_t)(bx + ty + i) * n + by + tx] = t[tx][ty + i];
}

// ---- transpose V bf16 [b*s][D] -> Vt [bh][hd][2048] ----
__global__ __launch_bounds__(256) void vtrans(const bf16* __restrict__ V, bf16* __restrict__ Vt) {
  constexpr int Sn = 2048, Dn = 1024;
  __shared__ bf16 t[32][33];
  int s0 = blockIdx.x * 32, hd0 = blockIdx.y * 32, bh = blockIdx.z;
  int b = bh >> 4, h = bh & 15;
  int tx = threadIdx.x & 31, ty = threadIdx.x >> 5;
#pragma unroll
  for (int i = 0; i < 32; i += 8)
    t[ty + i][tx] = V[(size_t)(b * Sn + s0 + ty + i) * Dn + h * 64 + hd0 + tx];
  __syncthreads();
#pragma unroll
  for (int i = 0; i < 32; i += 8)
    Vt[(size_t)bh * 64 * Sn + (size_t)(hd0 + ty + i) * Sn + s0 + tx] = t[tx][ty + i];
}

// ---- GEMM C[M,N] = A[M,K] @ Bt^T (Bt = bf16 [N][K]); reg-prefetched k-loop ----
template <typename TA, typename TC>
__global__ __launch_bounds__(256) void gemm_bt3(const TA* __restrict__ A,
                                                const bf16* __restrict__ Bt0,
                                                const bf16* __restrict__ Bt1,
                                                const bf16* __restrict__ Bt2,
                                                TC* __restrict__ C0, TC* __restrict__ C1,
                                                TC* __restrict__ C2, int M, int N, int K,
                                                int nblk) {
  constexpr int LDA = 40, LDB = 40;
  __shared__ bf16 As[128 * LDA];
  __shared__ bf16 Bs[128 * LDB];
  int tid = threadIdx.x, wave = tid >> 6, lane = tid & 63;
  int la = lane & 15, quad = lane >> 4;
  int wr = (wave >> 1) * 64, wc = (wave & 1) * 64;
  int by = blockIdx.y;
  int sel = by / nblk;
  int n0 = (by - sel * nblk) * 128;
  const bf16* Bm = sel == 0 ? Bt0 : (sel == 1 ? Bt1 : Bt2);
  TC* C = sel == 0 ? C0 : (sel == 1 ? C1 : C2);
  const TA* Ab = A + (size_t)blockIdx.x * 128 * K;

  int ar[2], ac[2];
#pragma unroll
  for (int p = 0; p < 2; ++p) {
    int li = (tid + p * 256) * 8;
    ar[p] = li >> 5; ac[p] = li & 31;
  }

  f32x4 zero = {0.f, 0.f, 0.f, 0.f};
  f32x4 acc[4][4];
#pragma unroll
  for (int i = 0; i < 4; ++i)
#pragma unroll
    for (int j = 0; j < 4; ++j) acc[i][j] = zero;

  decltype(ldr((const TA*)nullptr)) pa[2];
  bf16x8 pb[2];
#pragma unroll
  for (int p = 0; p < 2; ++p) {
    pa[p] = ldr(&Ab[(size_t)ar[p] * K + ac[p]]);
    pb[p] = ldr(&Bm[(size_t)(n0 + ar[p]) * K + ac[p]]);
  }

  for (int k0 = 0; k0 < K; k0 += 32) {
#pragma unroll
    for (int p = 0; p < 2; ++p) {
      *(bf16x8*)&As[ar[p] * LDA + ac[p]] = cv(pa[p]);
      *(bf16x8*)&Bs[ar[p] * LDB + ac[p]] = pb[p];
    }
    __syncthreads();
    int k1 = k0 + 32;
    if (k1 < K) {
#pragma unroll
      for (int p = 0; p < 2; ++p) {
        pa[p] = ldr(&Ab[(size_t)ar[p] * K + k1 + ac[p]]);
        pb[p] = ldr(&Bm[(size_t)(n0 + ar[p]) * K + k1 + ac[p]]);
      }
    }
    bf16x8 af[4], bfr[4];
#pragma unroll
    for (int i = 0; i < 4; ++i)
      af[i] = *(const bf16x8*)&As[(wr + i * 16 + la) * LDA + quad * 8];
#pragma unroll
    for (int j = 0; j < 4; ++j)
      bfr[j] = *(const bf16x8*)&Bs[(wc + j * 16 + la) * LDB + quad * 8];
#pragma unroll
    for (int i = 0; i < 4; ++i)
#pragma unroll
      for (int j = 0; j < 4; ++j) acc[i][j] = MFMA16(af[i], bfr[j], acc[i][j]);
    __syncthreads();
  }
#pragma unroll
  for (int i = 0; i < 4; ++i) {
#pragma unroll
    for (int j = 0; j < 4; ++j) {
      int col = n0 + wc + j * 16 + la;
#pragma unroll
      for (int r = 0; r < 4; ++r) {
        int row = blockIdx.x * 128 + wr + i * 16 + quad * 4 + r;
        stC(C, (size_t)row * N + col, acc[i][j][r]);
      }
    }
  }
}

// ---- one flash tile-step for one q-segment (transposed scores S^T = K@Q^T) ----
__device__ __forceinline__ void seg_step(const bf16* __restrict__ Ksb,
                                         const bf16* __restrict__ Vsb,
                                         bf16* __restrict__ Psw, const bf16x8* aq,
                                         f32x4* o, float& m_l, float& l_l,
                                         int la, int quad, int kb, int q0, bool diag) {
  const int LDK = 72, LDP = 72;
  const float MASK = -3.0e4f;
  f32x4 zero = {0.f, 0.f, 0.f, 0.f};
  f32x4 s[4];
#pragma unroll
  for (int nt = 0; nt < 4; ++nt) {
    bf16x8 k0f = *(const bf16x8*)&Ksb[(nt * 16 + la) * LDK + quad * 8];
    bf16x8 k1f = *(const bf16x8*)&Ksb[(nt * 16 + la) * LDK + 32 + quad * 8];
    f32x4 z = zero;
    z = MFMA16(k0f, aq[0], z);
    z = MFMA16(k1f, aq[1], z);
    s[nt] = z;
  }
  if (diag) {
    int qa = q0 + la;  // q0 already includes wave*16 offset
#pragma unroll
    for (int nt = 0; nt < 4; ++nt)
#pragma unroll
      for (int r = 0; r < 4; ++r) {
        int ka = kb + nt * 16 + quad * 4 + r;
        s[nt][r] = (ka > qa) ? MASK : s[nt][r];
      }
  }
  float mx = m_l;
#pragma unroll
  for (int nt = 0; nt < 4; ++nt)
#pragma unroll
    for (int r = 0; r < 4; ++r) mx = fmaxf(mx, s[nt][r]);
  mx = fmaxf(mx, __shfl_xor(mx, 16, 64));
  mx = fmaxf(mx, __shfl_xor(mx, 32, 64));
  float alpha = exp2f(m_l - mx);
  float rs = 0.f;
#pragma unroll
  for (int nt = 0; nt < 4; ++nt)
#pragma unroll
    for (int r = 0; r < 4; ++r) {
      float p = exp2f(s[nt][r] - mx);
      s[nt][r] = p;
      rs += p;
    }
  rs += __shfl_xor(rs, 16, 64);
  rs += __shfl_xor(rs, 32, 64);
  l_l = l_l * alpha + rs;
  m_l = mx;
#pragma unroll
  for (int nt = 0; nt < 4; ++nt) {
    bf16x4v pk;
#pragma unroll
    for (int r = 0; r < 4; ++r) pk[r] = (bf16)s[nt][r];
    *(bf16x4v*)&Psw[la * LDP + nt * 16 + quad * 4] = pk;
  }
  float ab[4];
#pragma unroll
  for (int r = 0; r < 4; ++r) ab[r] = __shfl(alpha, quad * 4 + r, 64);
#pragma unroll
  for (int nt = 0; nt < 4; ++nt)
#pragma unroll
    for (int r = 0; r < 4; ++r) o[nt][r] *= ab[r];
#pragma unroll
  for (int kc = 0; kc < 2; ++kc) {
    bf16x8 ap = *(const bf16x8*)&Psw[la * LDP + kc * 32 + quad * 8];
#pragma unroll
    for (int nt = 0; nt < 4; ++nt) {
      bf16x8 bv = *(const bf16x8*)&Vsb[(nt * 16 + la) * LDK + kc * 32 + quad * 8];
      o[nt] = MFMA16(ap, bv, o[nt]);
    }
  }
}

// ---- flash attention, causal, HD=64; dual q-segment, shared staging, dbuf ----
// grid (16, 32): block owns q-tiles {31-p, p}; p chosen so CU-aliased partner
// (bx, by+16) gets the complementary pair -> per-CU load uniform by construction.
// Segment B's keys are a subset of A's: one staging serves both. LDS dbuf K/V ->
// 1 barrier/tile. Lane owns one q-row's softmax state per segment.
__global__ __launch_bounds__(256) void flash_attn(const bf16* __restrict__ Q,
                                                  const bf16* __restrict__ Kg,
                                                  const bf16* __restrict__ Vtg,
                                                  bf16* __restrict__ O) {
  constexpr int D = 1024, S = 2048;
  const int LDK = 72;
  const float MASK = -3.0e4f;
  const float SCL2 = 0.18033688011112042f;  // log2(e)/sqrt(64)
  __shared__ bf16 Ks[2][64 * 72];
  __shared__ bf16 Vs[2][64 * 72];
  __shared__ bf16 Ps[4][16 * 72];

  int bx = blockIdx.x, by = blockIdx.y;
  int p = (by & 16) ? (15 - bx) : bx;
  int qtA = 31 - p, qtB = p;
  int b = by >> 4, h = by & 15;
  int tid = threadIdx.x, wave = tid >> 6, lane = tid & 63;
  int la = lane & 15, quad = lane >> 4;
  int q0A = qtA * 64 + wave * 16, q0B = qtB * 64 + wave * 16;
  const size_t base = (size_t)b * S * D + (size_t)h * 64;
  const bf16* Qg = Q + base;
  const bf16* Kb = Kg + base;
  const bf16* Vb = Vtg + (size_t)by * 64 * S;  // [hd][s]
  int r0 = tid >> 3, c0 = (tid & 7) * 8;

  // Q B-frags for both segments (pre-scaled by SCL2)
  bf16x8 aqA[2], aqB[2];
#pragma unroll
  for (int kc = 0; kc < 2; ++kc) {
    bf16x8 ta = *(const bf16x8*)&Qg[(size_t)(q0A + la) * D + kc * 32 + quad * 8];
    bf16x8 tb = *(const bf16x8*)&Qg[(size_t)(q0B + la) * D + kc * 32 + quad * 8];
#pragma unroll
    for (int i = 0; i < 8; ++i) {
      ta[i] = (bf16)((float)ta[i] * SCL2);
      tb[i] = (bf16)((float)tb[i] * SCL2);
    }
    aqA[kc] = ta; aqB[kc] = tb;
  }

  f32x4 zero = {0.f, 0.f, 0.f, 0.f};
  f32x4 oA[4], oB[4];
  float mA = MASK, lA = 0.f, mB = MASK, lB = 0.f;
#pragma unroll
  for (int nt = 0; nt < 4; ++nt) { oA[nt] = zero; oB[nt] = zero; }

  // prefetch tile 0 -> buf 0
  bf16x8 kr0 = *(const bf16x8*)&Kb[(size_t)r0 * D + c0];
  bf16x8 kr1 = *(const bf16x8*)&Kb[(size_t)(r0 + 32) * D + c0];
  bf16x8 vr0 = *(const bf16x8*)&Vb[(size_t)r0 * S + c0];
  bf16x8 vr1 = *(const bf16x8*)&Vb[(size_t)(r0 + 32) * S + c0];
  *(bf16x8*)&Ks[0][r0 * LDK + c0] = kr0;
  *(bf16x8*)&Ks[0][(r0 + 32) * LDK + c0] = kr1;
  *(bf16x8*)&Vs[0][r0 * LDK + c0] = vr0;
  *(bf16x8*)&Vs[0][(r0 + 32) * LDK + c0] = vr1;
  __syncthreads();

  int ntA = qtA + 1;
  for (int t = 0; t < ntA; ++t) {
    int kb = t * 64;
    int cur = t & 1, nxt = cur ^ 1;
    bool more = (t + 1 < ntA);
    if (more) {  // issue next tile's loads early; land behind compute
      int kb2 = kb + 64;
      kr0 = *(const bf16x8*)&Kb[(size_t)(kb2 + r0) * D + c0];
      kr1 = *(const bf16x8*)&Kb[(size_t)(kb2 + r0 + 32) * D + c0];
      vr0 = *(const bf16x8*)&Vb[(size_t)r0 * S + kb2 + c0];
      vr1 = *(const bf16x8*)&Vb[(size_t)(r0 + 32) * S + kb2 + c0];
    }
    seg_step(Ks[cur], Vs[cur], Ps[wave], aqA, oA, mA, lA, la, quad, kb, q0A, t == qtA);
    if (t <= qtB)
      seg_step(Ks[cur], Vs[cur], Ps[wave], aqB, oB, mB, lB, la, quad, kb, q0B, t == qtB);
    if (more) {
      *(bf16x8*)&Ks[nxt][r0 * LDK + c0] = kr0;
      *(bf16x8*)&Ks[nxt][(r0 + 32) * LDK + c0] = kr1;
      *(bf16x8*)&Vs[nxt][r0 * LDK + c0] = vr0;
      *(bf16x8*)&Vs[nxt][(r0 + 32) * LDK + c0] = vr1;
      __syncthreads();  // single barrier per tile (dbuf)
    }
  }

  // epilogue for both segments
#pragma unroll
  for (int seg = 0; seg < 2; ++seg) {
    f32x4* o = seg == 0 ? oA : oB;
    float l_l = seg == 0 ? lA : lB;
    int q0 = seg == 0 ? q0A : q0B;
    float inv[4];
#pragma unroll
    for (int r = 0; r < 4; ++r) {
      float lv = __shfl(l_l, quad * 4 + r, 64);
      inv[r] = (lv > 1e-30f) ? 1.0f / lv : 0.0f;
    }
#pragma unroll
    for (int nt = 0; nt < 4; ++nt) {
      int hd = nt * 16 + la;
#pragma unroll
      for (int r = 0; r < 4; ++r) {
        int row = q0 + quad * 4 + r;
        O[base + (size_t)row * D + hd] = (bf16)(o[nt][r] * inv[r]);
      }
    }
  }
}

extern "C" void kernel_launch(void* const* d_in, const int* in_sizes, int n_in,
                              void* d_out, int out_size, void* d_ws, size_t ws_size,
                              hipStream_t stream) {
  constexpr int B = 2, S = 2048, D = 1024;
  constexpr int M = B * S;
  constexpr size_t WN = (size_t)D * D;
  constexpr size_t XN = (size_t)M * D;

  const float* x = (const float*)d_in[0];
  const float* Wq = (const float*)d_in[1];
  const float* Wk = (const float*)d_in[2];
  const float* Wv = (const float*)d_in[3];
  const float* Wo = (const float*)d_in[4];
  float* out = (float*)d_out;

  if (ws_size < 2 * XN * sizeof(bf16)) return;
  bf16* Qb = (bf16*)d_ws;   // ws[0,8MB): Q, then O (flash aliases)
  bf16* R2 = Qb + XN;       // ws[8,16MB): time-shared: W^T(6MB) -> Vtg(8MB) -> Wo^T(2MB)
  bf16* Kb = (bf16*)d_out;  // d_out[0,8MB): K (dead before final gemm writes)
  bf16* Vb = Kb + XN;       // d_out[8,16MB): V (dead after vtrans)

  prep_wt<<<dim3(32, 32, 3), 256, 0, stream>>>(Wq, Wk, Wv, R2, D);
  gemm_bt3<float, bf16><<<dim3(M / 128, 24), 256, 0, stream>>>(
      x, R2, R2 + WN, R2 + 2 * WN, Qb, Kb, Vb, M, D, D, 8);
  vtrans<<<dim3(S / 32, 2, 32), 256, 0, stream>>>(Vb, R2);
  flash_attn<<<dim3(16, 32), 256, 0, stream>>>(Qb, Kb, R2, Qb);
  prep_wt<<<dim3(32, 32, 1), 256, 0, stream>>>(Wo, Wo, Wo, R2, D);
  gemm_bt3<bf16, float><<<dim3(M / 128, 8), 256, 0, stream>>>(
      Qb, R2, R2, R2, out, out, out, M, D, D, 8);
}